// Round 6
// baseline (239.552 us; speedup 1.0000x reference)
//
#include <hip/hip_runtime.h>

typedef _Float16 half8   __attribute__((ext_vector_type(8)));
typedef float    floatx4 __attribute__((ext_vector_type(4)));
typedef float    floatx16 __attribute__((ext_vector_type(16)));
typedef unsigned uintx2  __attribute__((ext_vector_type(2)));

#define LOG2E 1.44269504088896340736f

#define NQ  2048
#define NK  2048
#define DIM 512
#define KT  32
#define NTILES 64
#define IMG_BYTES 32768                     // 32 k x 512 d f16, [16][16]-subtiled
#define WS_NEED ((size_t)8 * NTILES * IMG_BYTES)   // 16 MiB

#define PKRT(a,b) __builtin_bit_cast(unsigned, __builtin_amdgcn_cvt_pkrtz((a),(b)))

// ---------------------------------------------------------------------------
// Image layout: f16 offset(k,d) = ((k>>4)*32 + (d>>4))*256 + (k&15)*16 + (d&15)
// ([kb][db][kr][dr] 16x16 subtiles, row-major inside). Byte:
//   (kb*32+db)*512 + kr*32 + dr*2.
//  - QK^T A-frag (row = k = lane&31, 8 contiguous d): plain ds_read_b128.
//  - PV A-frag (row = d = lane&31, 8 contiguous k): ds_read_b64_tr_b16 pairs.
// R6 (fixes R5's OOB crash: 512 blocks x 64 q-rows = 4096 > NQ):
//  - block = 32 q-rows, 4 waves, wave = d-QUARTER (128 d). 512 blocks x 32 q
//    = 2048 = NQ. Grid/geometry consistent.
//  - d-partial exchange: single-round 4-way butterfly (1 barrier).
//  - LDS = 2x32KB dbuf + 16KB sSx = 80KB -> 2 blocks/CU
//    (phase-decorrelated blocks fill each other's barrier stalls).
//  - prep kernel: XOR-swizzled LDS bounce (write conflict-free, read 2-way).
// Inner-loop math byte-identical to R4-verified kernel with dh*8192 ->
// wave*4096 (d-quarter base), loop trip counts halved.
// ---------------------------------------------------------------------------

// ============================ prep kernel ==================================
__global__ __launch_bounds__(256, 2)
void prep_k(const float* __restrict__ Kg, char* __restrict__ wsK)
{
    __shared__ __align__(16) char sLin[KT * DIM * 2];   // 32 KiB, row-major + swz
    const int tid  = threadIdx.x;
    const int lane = tid & 63;
    const int wave = tid >> 6;               // 0..3
    const int tileIdx = blockIdx.x;          // batch*64 + kt
    const int batch = tileIdx >> 6;
    const int kt    = tileIdx & 63;

    const float* base = Kg + ((size_t)batch * NK + (size_t)kt * KT) * DIM;
    char* img = wsK + (size_t)tileIdx * IMG_BYTES;

    // stage: wave reads row k as 2KB contiguous, converts to f16, writes 1KB
    // row with group-swizzle g' = g ^ ((k&7)<<3)  (write conflict-free)
    #pragma unroll
    for (int i = 0; i < 8; ++i) {
        const int k = wave * 8 + i;
        const float* kp = base + (size_t)k * DIM + lane * 8;
        float4 f0 = *(const float4*)(kp + 0);
        float4 f1 = *(const float4*)(kp + 4);
        uint4 w;
        w.x = PKRT(f0.x, f0.y); w.y = PKRT(f0.z, f0.w);
        w.z = PKRT(f1.x, f1.y); w.w = PKRT(f1.z, f1.w);
        *(uint4*)&sLin[k * 1024 + ((lane ^ ((k & 7) << 3)) * 16)] = w;
    }
    __syncthreads();

    // gather into image order (coalesced 4KB global chunks); LDS reads 2-way
    #pragma unroll
    for (int i = 0; i < 8; ++i) {
        const int o   = i * 4096 + tid * 16;        // image byte offset
        const int sub = o >> 9;                     // kb*32 + db
        const int kr  = (o >> 5) & 15;
        const int b   = (o >> 4) & 1;
        const int kb  = sub >> 5;
        const int db  = sub & 31;
        const int row = kb * 16 + kr;
        const int g   = db * 2 + b;                 // 16B group within row
        const int src = row * 1024 + ((g ^ ((row & 7) << 3)) * 16);
        *(uint4*)(img + o) = *(const uint4*)&sLin[src];
    }
}

// ============================ main kernel ==================================
__device__ __forceinline__ void gld16(const char* g, char* l)
{
    __builtin_amdgcn_global_load_lds(
        (const __attribute__((address_space(1))) void*)g,
        (__attribute__((address_space(3))) void*)l, 16, 0, 0);
}

__global__ __launch_bounds__(256, 2)
void attn_fa6(const float* __restrict__ Qg, const char* __restrict__ wsK,
              float* __restrict__ Og)
{
    __shared__ __align__(16) char  sK[2][IMG_BYTES];   // 64 KiB double buffer
    __shared__ __align__(16) float sSx[4096];          // 16 KiB -> 80 KiB total

    const int tid  = threadIdx.x;
    const int lane = tid & 63;
    const int wave = tid >> 6;          // 0..3 = d-quarter
    const int ql   = lane & 31;
    const int h    = lane >> 5;

    const int batch = blockIdx.x & 7;   // batch -> XCD: image resident in one L2
    const int qtile = blockIdx.x >> 3;  // 0..63  (32 q-rows each: 64*32 = 2048)
    const int qrow  = qtile * 32 + ql;
    const int dqb   = wave * 4096;      // d-quarter byte base (within kb-half)

    const char* img = wsK + (size_t)(batch * NTILES) * IMG_BYTES;

    // ---- Q fragments (B-layout): lane holds Q[qrow][wave*128 + dc*16 + h*8 + j]
    const float* qp = Qg + ((size_t)batch * NQ + qrow) * DIM + wave * 128 + h * 8;
    half8 qf[8];
    #pragma unroll
    for (int dc = 0; dc < 8; ++dc) {
        float4 f0 = *(const float4*)(qp + dc * 16);
        float4 f1 = *(const float4*)(qp + dc * 16 + 4);
        union { unsigned u[4]; half8 hh; } t;
        t.u[0] = PKRT(f0.x, f0.y); t.u[1] = PKRT(f0.z, f0.w);
        t.u[2] = PKRT(f1.x, f1.y); t.u[3] = PKRT(f1.z, f1.w);
        qf[dc] = t.hh;
    }
    asm volatile("" ::: "memory");   // keep Q loads/waits ahead of the DMA queue

    floatx16 acc[4];
    #pragma unroll
    for (int dt = 0; dt < 4; ++dt) {
        #pragma unroll
        for (int e = 0; e < 16; ++e) acc[dt][e] = 0.f;
    }
    float m_run = -INFINITY;
    float l_run = 0.f;

    // lane-constant LDS offsets (bytes)
    const int laneA = ((lane >> 4) & 1) * 16384 + (lane & 15) * 32 + h * 16;
    const int laneT = ((lane >> 4) & 1) * 512 + h * 256 + (lane & 15) * 8;

    // stage one 32KB image: 4 waves x 8 chunks of 1KB
    auto issue = [&](int t, int bi) {
        const char* src = img + (size_t)t * IMG_BYTES;
        char* dst = &sK[bi][0];
        const int cw = wave * 8;
        #pragma unroll
        for (int i = 0; i < 8; ++i) {
            const int c = cw + i;
            gld16(src + c * 1024 + lane * 16, dst + c * 1024);
        }
    };

    issue(0, 0);   // prologue prefetch

    for (int kt = 0; kt < NTILES; ++kt) {
        const int bi = kt & 1;
        issue((kt + 1) & (NTILES - 1), bi ^ 1);   // prefetch next tile

        asm volatile("s_waitcnt vmcnt(8)" ::: "memory");  // own current-tile chunks
        __builtin_amdgcn_s_barrier();
        __builtin_amdgcn_sched_barrier(0);

        const char* buf = &sK[bi][0];

        // ---- QK^T partial over this wave's d-quarter: S^T[32k][32q] ----
        union SS { floatx16 v; floatx4 q[4]; float f[16]; } s;
        {
            floatx16 sv;
            #pragma unroll
            for (int e = 0; e < 16; ++e) sv[e] = 0.f;
            const char* ap = buf + dqb + laneA;
            __builtin_amdgcn_s_setprio(1);
            #pragma unroll
            for (int dc = 0; dc < 8; ++dc) {
                half8 a = *(const half8*)(ap + dc * 512);
                sv = __builtin_amdgcn_mfma_f32_32x32x16_f16(a, qf[dc], sv, 0, 0, 0);
            }
            __builtin_amdgcn_s_setprio(0);
            s.v = sv;
        }

        // ---- combine 4 d-quarter partials: single-round butterfly ----
        {
            float* wp = sSx + wave * 1024 + lane * 4;   // lane-contiguous 1KB/part
            *(floatx4*)(wp + 0)   = s.q[0];
            *(floatx4*)(wp + 256) = s.q[1];
            *(floatx4*)(wp + 512) = s.q[2];
            *(floatx4*)(wp + 768) = s.q[3];
        }
        asm volatile("s_waitcnt lgkmcnt(0)" ::: "memory");
        __builtin_amdgcn_s_barrier();
        __builtin_amdgcn_sched_barrier(0);
        #pragma unroll
        for (int p = 1; p < 4; ++p) {
            const float* rp = sSx + (wave ^ p) * 1024 + lane * 4;
            s.q[0] += *(const floatx4*)(rp + 0);
            s.q[1] += *(const floatx4*)(rp + 256);
            s.q[2] += *(const floatx4*)(rp + 512);
            s.q[3] += *(const floatx4*)(rp + 768);
        }

        // ---- online softmax with defer-max (q = lane&31 lane-local) ----
        float mloc = s.f[0];
        #pragma unroll
        for (int r = 1; r < 16; ++r) mloc = fmaxf(mloc, s.f[r]);
        mloc = fmaxf(mloc, __shfl_xor(mloc, 32));
        if (!__all(mloc <= m_run + 8.f)) {       // rescale only on real growth
            const float m_new = fmaxf(m_run, mloc);
            const float alpha = exp2f((m_run - m_new) * LOG2E);
            l_run *= alpha;
            #pragma unroll
            for (int dt = 0; dt < 4; ++dt) acc[dt] *= alpha;
            m_run = m_new;
        }

        float sl = 0.f;
        unsigned pk[8];
        #pragma unroll
        for (int s8 = 0; s8 < 8; ++s8) {
            const float pa = exp2f((s.f[2 * s8]     - m_run) * LOG2E);
            const float pb = exp2f((s.f[2 * s8 + 1] - m_run) * LOG2E);
            sl += pa + pb;
            pk[s8] = PKRT(pa, pb);
        }
        sl += __shfl_xor(sl, 32);
        l_run += sl;

        // ---- P^T B-fragments (k rows, q cols) via cross-half shuffles ----
        unsigned sw[8];
        #pragma unroll
        for (int s8 = 0; s8 < 8; ++s8)
            sw[s8] = (unsigned)__shfl_xor((int)pk[s8], 32);
        union PB { unsigned u[4]; half8 hh; } b0, b1;
        b0.u[0] = h ? sw[2] : pk[0];  b0.u[1] = h ? sw[3] : pk[1];
        b0.u[2] = h ? pk[2] : sw[0];  b0.u[3] = h ? pk[3] : sw[1];
        b1.u[0] = h ? sw[6] : pk[4];  b1.u[1] = h ? sw[7] : pk[5];
        b1.u[2] = h ? pk[6] : sw[4];  b1.u[3] = h ? pk[7] : sw[5];

        // ---- O^T += K^T . P^T over this wave's d-quarter (tr-reads) ----
        const unsigned bufA =
            (unsigned)(size_t)(__attribute__((address_space(3))) const char*)buf
            + (unsigned)(dqb + laneT);
        __builtin_amdgcn_s_setprio(1);
        #pragma unroll
        for (int dt = 0; dt < 4; ++dt) {
            uintx2 t0, t1, t2, t3;
            const unsigned a0 = bufA + dt * 1024;        // kb = 0
            const unsigned a1 = a0 + 16384;              // kb = 1
            asm volatile(
                "ds_read_b64_tr_b16 %0, %4\n\t"
                "ds_read_b64_tr_b16 %1, %4 offset:128\n\t"
                "ds_read_b64_tr_b16 %2, %5\n\t"
                "ds_read_b64_tr_b16 %3, %5 offset:128"
                : "=&v"(t0), "=&v"(t1), "=&v"(t2), "=&v"(t3)
                : "v"(a0), "v"(a1));
            asm volatile("s_waitcnt lgkmcnt(0)" ::: "memory");
            __builtin_amdgcn_sched_barrier(0);
            union AF { uintx2 d[2]; half8 hh; } A0, A1;
            A0.d[0] = t0; A0.d[1] = t1;
            A1.d[0] = t2; A1.d[1] = t3;
            acc[dt] = __builtin_amdgcn_mfma_f32_32x32x16_f16(A0.hh, b0.hh, acc[dt], 0, 0, 0);
            acc[dt] = __builtin_amdgcn_mfma_f32_32x32x16_f16(A1.hh, b1.hh, acc[dt], 0, 0, 0);
        }
        __builtin_amdgcn_s_setprio(0);

        __builtin_amdgcn_s_barrier();    // all waves done with sK[bi] + sSx
        __builtin_amdgcn_sched_barrier(0);
    }

    // ---- epilogue: pure register normalize + store this d-quarter ----
    {
        const float inv = 1.f / l_run;
        float* op = Og + ((size_t)batch * NQ + qrow) * DIM + wave * 128;
        #pragma unroll
        for (int dt = 0; dt < 4; ++dt) {
            union SS2 { floatx16 v; floatx4 q[4]; } w;
            w.v = acc[dt] * inv;
            #pragma unroll
            for (int g = 0; g < 4; ++g)
                *(floatx4*)(op + dt * 32 + g * 8 + 4 * h) = w.q[g];
        }
    }
}

// ==================== legacy fallback (verified, 272 us) ====================
__global__ __launch_bounds__(256, 2)
void attn_fa(const float* __restrict__ Qg, const float* __restrict__ Kg,
             float* __restrict__ Og)
{
    __shared__ __align__(16) _Float16 sKr[KT * 512];
    __shared__ __align__(16) _Float16 sKt[256 * 72];
    __shared__ __align__(16) float    sSx[4 * 2 * 64 * 4];

    const int tid  = threadIdx.x;
    const int lane = tid & 63;
    const int wave = tid >> 6;
    const int quad = lane >> 4;
    const int col  = lane & 15;
    const int wq   = wave & 1;
    const int wg   = wave >> 1;
    const int dbase = wg * 256;

    const int batch = blockIdx.x & 7;
    const int qtile = blockIdx.x >> 3;
    const int qrow  = qtile * 32 + wq * 16 + col;

    const float* qp = Qg + ((size_t)batch * NQ + qrow) * DIM + dbase + quad * 8;
    half8 qf[8];
    #pragma unroll
    for (int dc = 0; dc < 8; ++dc) {
        float4 f0 = *(const float4*)(qp + dc * 32);
        float4 f1 = *(const float4*)(qp + dc * 32 + 4);
        union { unsigned u[4]; half8 hh; } t;
        t.u[0] = PKRT(f0.x, f0.y); t.u[1] = PKRT(f0.z, f0.w);
        t.u[2] = PKRT(f1.x, f1.y); t.u[3] = PKRT(f1.z, f1.w);
        qf[dc] = t.hh;
    }

    floatx4 acc[16];
    #pragma unroll
    for (int i = 0; i < 16; ++i) acc[i] = (floatx4){0.f, 0.f, 0.f, 0.f};

    float m_run = -INFINITY;
    float l_run = 0.f;
    const int keyc = ((col & 3) << 1) | ((col >> 2) & 1);

    for (int kt = 0; kt < NK / KT; ++kt) {
        __syncthreads();
        {
            const float* kp = Kg + ((size_t)batch * NK + kt * KT + wave * 8) * DIM + lane * 8;
            float rv[8][8];
            #pragma unroll
            for (int kk = 0; kk < 8; ++kk) {
                float4 f0 = *(const float4*)(kp + kk * DIM);
                float4 f1 = *(const float4*)(kp + kk * DIM + 4);
                rv[kk][0] = f0.x; rv[kk][1] = f0.y; rv[kk][2] = f0.z; rv[kk][3] = f0.w;
                rv[kk][4] = f1.x; rv[kk][5] = f1.y; rv[kk][6] = f1.z; rv[kk][7] = f1.w;
            }
            #pragma unroll
            for (int kk = 0; kk < 8; ++kk) {
                const int row = wave * 8 + kk;
                const int key = ((row & 3) << 1) | ((row >> 2) & 1);
                uint4 w;
                w.x = PKRT(rv[kk][0], rv[kk][1]); w.y = PKRT(rv[kk][2], rv[kk][3]);
                w.z = PKRT(rv[kk][4], rv[kk][5]); w.w = PKRT(rv[kk][6], rv[kk][7]);
                *(uint4*)&sKr[row * 512 + ((lane ^ key) << 3)] = w;
            }
            #pragma unroll
            for (int dd = 0; dd < 8; ++dd) {
                const int pp = dd >> 1;
                const int b  = dd & 1;
                const int slot = (pp << 6) | lane;
                uint4 w;
                w.x = PKRT(rv[0][dd], rv[1][dd]); w.y = PKRT(rv[2][dd], rv[3][dd]);
                w.z = PKRT(rv[4][dd], rv[5][dd]); w.w = PKRT(rv[6][dd], rv[7][dd]);
                *(uint4*)&sKt[slot * 72 + ((wave ^ pp) << 4) + (b << 3)] = w;
            }
        }
        __syncthreads();

        floatx4 s0 = {0.f, 0.f, 0.f, 0.f}, s1 = {0.f, 0.f, 0.f, 0.f};
        #pragma unroll
        for (int dc = 0; dc < 8; ++dc) {
            const int g = wg * 32 + dc * 4 + quad;
            const int off = ((g ^ keyc) << 3);
            half8 a0 = *(const half8*)&sKr[col * 512 + off];
            half8 a1 = *(const half8*)&sKr[(col + 16) * 512 + off];
            s0 = __builtin_amdgcn_mfma_f32_16x16x32_f16(a0, qf[dc], s0, 0, 0, 0);
            s1 = __builtin_amdgcn_mfma_f32_16x16x32_f16(a1, qf[dc], s1, 0, 0, 0);
        }

        *(floatx4*)&sSx[((wave * 2 + 0) * 64 + lane) * 4] = s0;
        *(floatx4*)&sSx[((wave * 2 + 1) * 64 + lane) * 4] = s1;
        __syncthreads();
        {
            const int pw = wave ^ 2;
            s0 += *(const floatx4*)&sSx[((pw * 2 + 0) * 64 + lane) * 4];
            s1 += *(const floatx4*)&sSx[((pw * 2 + 1) * 64 + lane) * 4];
        }

        float mloc = fmaxf(fmaxf(fmaxf(s0[0], s0[1]), fmaxf(s0[2], s0[3])),
                           fmaxf(fmaxf(s1[0], s1[1]), fmaxf(s1[2], s1[3])));
        mloc = fmaxf(mloc, __shfl_xor(mloc, 16));
        mloc = fmaxf(mloc, __shfl_xor(mloc, 32));
        const float m_new = fmaxf(m_run, mloc);
        const float alpha = exp2f((m_run - m_new) * LOG2E);
        const float p0 = exp2f((s0[0] - m_new) * LOG2E);
        const float p1 = exp2f((s0[1] - m_new) * LOG2E);
        const float p2 = exp2f((s0[2] - m_new) * LOG2E);
        const float p3 = exp2f((s0[3] - m_new) * LOG2E);
        const float p4 = exp2f((s1[0] - m_new) * LOG2E);
        const float p5 = exp2f((s1[1] - m_new) * LOG2E);
        const float p6 = exp2f((s1[2] - m_new) * LOG2E);
        const float p7 = exp2f((s1[3] - m_new) * LOG2E);
        float sloc = ((p0 + p1) + (p2 + p3)) + ((p4 + p5) + (p6 + p7));
        sloc += __shfl_xor(sloc, 16);
        sloc += __shfl_xor(sloc, 32);
        l_run = l_run * alpha + sloc;
        m_run = m_new;

        #pragma unroll
        for (int i = 0; i < 16; ++i) acc[i] *= alpha;

        const unsigned pk00 = PKRT(p0, p1);
        const unsigned pk01 = PKRT(p2, p3);
        const unsigned pk10 = PKRT(p4, p5);
        const unsigned pk11 = PKRT(p6, p7);
        const int srcA = col + ((quad & 1) << 5);
        const int srcB = srcA + 16;
        const unsigned a00 = (unsigned)__shfl((int)pk00, srcA);
        const unsigned a01 = (unsigned)__shfl((int)pk01, srcA);
        const unsigned a10 = (unsigned)__shfl((int)pk10, srcA);
        const unsigned a11 = (unsigned)__shfl((int)pk11, srcA);
        const unsigned b00 = (unsigned)__shfl((int)pk00, srcB);
        const unsigned b01 = (unsigned)__shfl((int)pk01, srcB);
        const unsigned b10 = (unsigned)__shfl((int)pk10, srcB);
        const unsigned b11 = (unsigned)__shfl((int)pk11, srcB);
        const bool hi2 = (quad >= 2);
        union { unsigned u[4]; half8 hh; } pt;
        pt.u[0] = hi2 ? a10 : a00;
        pt.u[1] = hi2 ? a11 : a01;
        pt.u[2] = hi2 ? b10 : b00;
        pt.u[3] = hi2 ? b11 : b01;
        const half8 pf = pt.hh;

        #pragma unroll
        for (int dt = 0; dt < 16; ++dt) {
            const int drow = dbase + dt * 16 + col;
            const int dp = drow >> 1;
            const int off = (((dp & 3) << 6) | (dp >> 2)) * 72
                          + ((quad ^ (dp & 3)) << 4) + ((drow & 1) << 3);
            half8 af = *(const half8*)&sKt[off];
            acc[dt] = __builtin_amdgcn_mfma_f32_16x16x32_f16(af, pf, acc[dt], 0, 0, 0);
        }
    }

    const float inv = 1.f / l_run;
    float* op = Og + ((size_t)batch * NQ + qrow) * DIM + dbase + quad * 4;
    #pragma unroll
    for (int dt = 0; dt < 16; ++dt) {
        floatx4 v = acc[dt] * inv;
        *(floatx4*)(op + dt * 16) = v;
    }
}

extern "C" void kernel_launch(void* const* d_in, const int* in_sizes, int n_in,
                              void* d_out, int out_size, void* d_ws, size_t ws_size,
                              hipStream_t stream) {
    (void)in_sizes; (void)n_in; (void)out_size;
    const float* Q = (const float*)d_in[0];
    const float* K = (const float*)d_in[1];
    float* O = (float*)d_out;
    if (d_ws != nullptr && ws_size >= WS_NEED) {
        char* wsK = (char*)d_ws;
        hipLaunchKernelGGL(prep_k,   dim3(8 * NTILES), dim3(256), 0, stream, K, wsK);
        hipLaunchKernelGGL(attn_fa6, dim3(512),        dim3(256), 0, stream, Q, wsK, O);
    } else {
        hipLaunchKernelGGL(attn_fa,  dim3(512),        dim3(256), 0, stream, Q, K, O);
    }
}

// Round 7
// 203.855 us; speedup vs baseline: 1.1751x; 1.1751x over previous
//
#include <hip/hip_runtime.h>

typedef _Float16 half8   __attribute__((ext_vector_type(8)));
typedef float    floatx4 __attribute__((ext_vector_type(4)));
typedef float    floatx16 __attribute__((ext_vector_type(16)));
typedef unsigned uintx2  __attribute__((ext_vector_type(2)));

#define LOG2E 1.44269504088896340736f

#define NQ  2048
#define NK  2048
#define DIM 512
#define KT  32
#define NTILES 64
#define IMG_BYTES 32768                     // 32 k x 512 d f16, [16][16]-subtiled
#define WS_NEED ((size_t)8 * NTILES * IMG_BYTES)   // 16 MiB

#define PKRT(a,b) __builtin_bit_cast(unsigned, __builtin_amdgcn_cvt_pkrtz((a),(b)))

// ---------------------------------------------------------------------------
// Image layout: f16 offset(k,d) = ((k>>4)*32 + (d>>4))*256 + (k&15)*16 + (d&15)
// ([kb][db][kr][dr] 16x16 subtiles, row-major inside). Byte:
//   (kb*32+db)*512 + kr*32 + dr*2.
//  - QK^T A-frag (row = k = lane&31, 8 contiguous d): plain ds_read_b128.
//  - PV A-frag (row = d = lane&31, 8 contiguous k): ds_read_b64_tr_b16 pairs.
// R7 = R4 (best verified, 128 us main) + two inspection-verified fixes:
//  1. prep gather swizzle key corrected: (row&7)<<3 made row stride
//     1152B = 0 mod 128B (16-way conflict). Correct key = row&15 (unshifted):
//     write pos = lane^(k&15), read pos = g^(row&15) -> uniform bank spread.
//  2. barrier-merge: issue(t+1) AFTER the stage-ready barrier. bar1(t)
//     already orders all waves past iter t-1's buffer/sSx reads, so the
//     end-of-iter barrier is redundant -> 2 barriers/iter instead of 3.
//     vmcnt(0) at top waits loads issued a full iteration ago (no stall).
//     Last-iter prefetch guarded off (no in-flight DMA at endpgm).
// R6 lesson (counters): d-split waves replicate softmax VALU 512/d times;
// (32q, 256d) is the unique point with repl=2 and acc<=128 VGPR. Keep R4.
// ---------------------------------------------------------------------------

// ============================ prep kernel ==================================
__global__ __launch_bounds__(256, 2)
void prep_k(const float* __restrict__ Kg, char* __restrict__ wsK)
{
    __shared__ __align__(16) char sLin[KT * DIM * 2];   // 32 KiB
    const int tid  = threadIdx.x;
    const int lane = tid & 63;
    const int wave = tid >> 6;               // 0..3
    const int tileIdx = blockIdx.x;          // batch*64 + kt
    const int batch = tileIdx >> 6;
    const int kt    = tileIdx & 63;

    const float* base = Kg + ((size_t)batch * NK + (size_t)kt * KT) * DIM;
    char* img = wsK + (size_t)tileIdx * IMG_BYTES;

    // stage: wave reads row k as 2KB contiguous (coalesced), converts to f16,
    // writes 1KB row with granule permutation pos = lane ^ (k&15)
    // (bijective -> conflict-free write)
    #pragma unroll
    for (int i = 0; i < 8; ++i) {
        const int k = wave * 8 + i;
        const float* kp = base + (size_t)k * DIM + lane * 8;
        float4 f0 = *(const float4*)(kp + 0);
        float4 f1 = *(const float4*)(kp + 4);
        uint4 w;
        w.x = PKRT(f0.x, f0.y); w.y = PKRT(f0.z, f0.w);
        w.z = PKRT(f1.x, f1.y); w.w = PKRT(f1.z, f1.w);
        *(uint4*)&sLin[k * 1024 + ((lane ^ (k & 15)) << 4)] = w;
    }
    __syncthreads();

    // gather into image order (coalesced 4KB global chunks);
    // LDS read pos = g ^ (row&15): uniform bank distribution (floor)
    #pragma unroll
    for (int i = 0; i < 8; ++i) {
        const int o   = i * 4096 + tid * 16;        // image byte offset
        const int sub = o >> 9;                     // kb*32 + db
        const int kr  = (o >> 5) & 15;
        const int b   = (o >> 4) & 1;
        const int kb  = sub >> 5;
        const int db  = sub & 31;
        const int row = kb * 16 + kr;
        const int g   = db * 2 + b;                 // 16B granule within row
        const int src = row * 1024 + ((g ^ (row & 15)) << 4);
        *(uint4*)(img + o) = *(const uint4*)&sLin[src];
    }
}

// ============================ main kernel ==================================
__device__ __forceinline__ void gld16(const char* g, char* l)
{
    __builtin_amdgcn_global_load_lds(
        (const __attribute__((address_space(1))) void*)g,
        (__attribute__((address_space(3))) void*)l, 16, 0, 0);
}

__global__ __launch_bounds__(512, 2)
void attn_fa7(const float* __restrict__ Qg, const char* __restrict__ wsK,
              float* __restrict__ Og)
{
    __shared__ __align__(16) char  sK[2][2][IMG_BYTES];   // [stream][buf] 128 KiB
    __shared__ __align__(16) float sSx[8192];             // 32 KiB -> 160 KiB total

    const int tid  = threadIdx.x;
    const int lane = tid & 63;
    const int wave = tid >> 6;          // 0..7
    const int strip  = wave & 1;        // q-strip (32 rows)
    const int dh     = (wave >> 1) & 1; // d-half (256)
    const int stream = wave >> 2;       // k-split stream
    const int ql   = lane & 31;
    const int h    = lane >> 5;

    const int batch = blockIdx.x & 7;   // batch -> XCD: image resident in one L2
    const int qtile = blockIdx.x >> 3;  // 0..31
    const int qrow  = qtile * 64 + strip * 32 + ql;
    const int dbase = dh * 256;

    const char* img = wsK + ((size_t)(batch * NTILES + stream * 32)) * IMG_BYTES;

    // ---- Q fragments (B-layout): lane holds Q[qrow][dbase + dc*16 + h*8 + j] ----
    const float* qp = Qg + ((size_t)batch * NQ + qrow) * DIM + dbase + h * 8;
    half8 qf[16];
    #pragma unroll
    for (int dc = 0; dc < 16; ++dc) {
        float4 f0 = *(const float4*)(qp + dc * 16);
        float4 f1 = *(const float4*)(qp + dc * 16 + 4);
        union { unsigned u[4]; half8 hh; } t;
        t.u[0] = PKRT(f0.x, f0.y); t.u[1] = PKRT(f0.z, f0.w);
        t.u[2] = PKRT(f1.x, f1.y); t.u[3] = PKRT(f1.z, f1.w);
        qf[dc] = t.hh;
    }
    asm volatile("" ::: "memory");   // keep Q loads/waits ahead of the DMA queue

    floatx16 acc[8];
    #pragma unroll
    for (int dt = 0; dt < 8; ++dt) {
        #pragma unroll
        for (int e = 0; e < 16; ++e) acc[dt][e] = 0.f;
    }
    float m_run = -INFINITY;
    float l_run = 0.f;

    // lane-constant LDS offsets (bytes)
    const int laneA = ((lane >> 4) & 1) * 16384 + (lane & 15) * 32 + h * 16;
    const int laneT = ((lane >> 4) & 1) * 512 + h * 256 + (lane & 15) * 8;

    // stage one 32KB image: 4 waves per stream x 8 chunks of 1KB
    auto issue = [&](int t, int bi) {
        const char* src = img + (size_t)t * IMG_BYTES;
        char* dst = &sK[stream][bi][0];
        const int cw = (wave & 3) * 8;
        #pragma unroll
        for (int i = 0; i < 8; ++i) {
            const int c = cw + i;
            gld16(src + c * 1024 + lane * 16, dst + c * 1024);
        }
    };

    issue(0, 0);   // prologue prefetch

    for (int kt = 0; kt < 32; ++kt) {
        const int bi = kt & 1;

        // current tile's loads were issued one full iteration ago -> no stall
        asm volatile("s_waitcnt vmcnt(0)" ::: "memory");
        __builtin_amdgcn_s_barrier();      // also orders iter t-1's buf/sSx reads
        __builtin_amdgcn_sched_barrier(0);

        if (kt != 31) issue(kt + 1, bi ^ 1);   // prefetch next tile, other buffer

        const char* buf = &sK[stream][bi][0];

        // ---- QK^T partial over this wave's d-half: S^T[32k][32q] ----
        union SS { floatx16 v; floatx4 q[4]; float f[16]; } s;
        {
            floatx16 sv;
            #pragma unroll
            for (int e = 0; e < 16; ++e) sv[e] = 0.f;
            const char* ap = buf + dh * 8192 + laneA;
            __builtin_amdgcn_s_setprio(1);
            #pragma unroll
            for (int dc = 0; dc < 16; ++dc) {
                half8 a = *(const half8*)(ap + dc * 512);
                sv = __builtin_amdgcn_mfma_f32_32x32x16_f16(a, qf[dc], sv, 0, 0, 0);
            }
            __builtin_amdgcn_s_setprio(0);
            s.v = sv;
        }

        // ---- combine d-half partials with partner wave (wave^2), 1 round ----
        {
            float* wp = sSx + wave * 1024 + lane * 4;   // lane-contiguous 1KB/part
            *(floatx4*)(wp + 0)   = s.q[0];
            *(floatx4*)(wp + 256) = s.q[1];
            *(floatx4*)(wp + 512) = s.q[2];
            *(floatx4*)(wp + 768) = s.q[3];
        }
        asm volatile("s_waitcnt lgkmcnt(0)" ::: "memory");
        __builtin_amdgcn_s_barrier();
        __builtin_amdgcn_sched_barrier(0);
        {
            const float* rp = sSx + (wave ^ 2) * 1024 + lane * 4;
            s.q[0] += *(const floatx4*)(rp + 0);
            s.q[1] += *(const floatx4*)(rp + 256);
            s.q[2] += *(const floatx4*)(rp + 512);
            s.q[3] += *(const floatx4*)(rp + 768);
        }

        // ---- online softmax with defer-max (q = lane&31 lane-local) ----
        float mloc = s.f[0];
        #pragma unroll
        for (int r = 1; r < 16; ++r) mloc = fmaxf(mloc, s.f[r]);
        mloc = fmaxf(mloc, __shfl_xor(mloc, 32));
        if (!__all(mloc <= m_run + 8.f)) {       // rescale only on real growth
            const float m_new = fmaxf(m_run, mloc);
            const float alpha = exp2f((m_run - m_new) * LOG2E);
            l_run *= alpha;
            #pragma unroll
            for (int dt = 0; dt < 8; ++dt) acc[dt] *= alpha;
            m_run = m_new;
        }

        float sl = 0.f;
        unsigned pk[8];
        #pragma unroll
        for (int s8 = 0; s8 < 8; ++s8) {
            const float pa = exp2f((s.f[2 * s8]     - m_run) * LOG2E);
            const float pb = exp2f((s.f[2 * s8 + 1] - m_run) * LOG2E);
            sl += pa + pb;
            pk[s8] = PKRT(pa, pb);
        }
        sl += __shfl_xor(sl, 32);
        l_run += sl;

        // ---- P^T B-fragments (k rows, q cols) via cross-half shuffles ----
        unsigned sw[8];
        #pragma unroll
        for (int s8 = 0; s8 < 8; ++s8)
            sw[s8] = (unsigned)__shfl_xor((int)pk[s8], 32);
        union PB { unsigned u[4]; half8 hh; } b0, b1;
        b0.u[0] = h ? sw[2] : pk[0];  b0.u[1] = h ? sw[3] : pk[1];
        b0.u[2] = h ? pk[2] : sw[0];  b0.u[3] = h ? pk[3] : sw[1];
        b1.u[0] = h ? sw[6] : pk[4];  b1.u[1] = h ? sw[7] : pk[5];
        b1.u[2] = h ? pk[6] : sw[4];  b1.u[3] = h ? pk[7] : sw[5];

        // ---- O^T += K^T . P^T, A-frags via hardware transpose reads ----
        const unsigned bufA =
            (unsigned)(size_t)(__attribute__((address_space(3))) const char*)buf
            + (unsigned)(dh * 8192 + laneT);
        __builtin_amdgcn_s_setprio(1);
        #pragma unroll
        for (int dt = 0; dt < 8; ++dt) {
            uintx2 t0, t1, t2, t3;
            const unsigned a0 = bufA + dt * 1024;        // kb = 0
            const unsigned a1 = a0 + 16384;              // kb = 1
            asm volatile(
                "ds_read_b64_tr_b16 %0, %4\n\t"
                "ds_read_b64_tr_b16 %1, %4 offset:128\n\t"
                "ds_read_b64_tr_b16 %2, %5\n\t"
                "ds_read_b64_tr_b16 %3, %5 offset:128"
                : "=&v"(t0), "=&v"(t1), "=&v"(t2), "=&v"(t3)
                : "v"(a0), "v"(a1));
            asm volatile("s_waitcnt lgkmcnt(0)" ::: "memory");
            __builtin_amdgcn_sched_barrier(0);
            union AF { uintx2 d[2]; half8 hh; } A0, A1;
            A0.d[0] = t0; A0.d[1] = t1;
            A1.d[0] = t2; A1.d[1] = t3;
            acc[dt] = __builtin_amdgcn_mfma_f32_32x32x16_f16(A0.hh, b0.hh, acc[dt], 0, 0, 0);
            acc[dt] = __builtin_amdgcn_mfma_f32_32x32x16_f16(A1.hh, b1.hh, acc[dt], 0, 0, 0);
        }
        __builtin_amdgcn_s_setprio(0);
        // no end-of-iter barrier: next iteration's bar1 provides the ordering
    }

    // ---- epilogue: merge the two k-streams (partner wave^4), store ----
    {
        sSx[(wave * 64 + lane) * 2 + 0] = m_run;
        sSx[(wave * 64 + lane) * 2 + 1] = l_run;
        __syncthreads();
        const float pm = sSx[((wave ^ 4) * 64 + lane) * 2 + 0];
        const float pl = sSx[((wave ^ 4) * 64 + lane) * 2 + 1];
        const float mt   = fmaxf(m_run, pm);
        const float aown = exp2f((m_run - mt) * LOG2E);
        const float aoth = exp2f((pm   - mt) * LOG2E);
        const float lt   = l_run * aown + pl * aoth;
        const float inv  = 1.f / lt;
        (void)aoth;
        __syncthreads();

        float* op = Og + ((size_t)batch * NQ + qrow) * DIM + dbase;
        #pragma unroll
        for (int dt = 0; dt < 8; ++dt) {
            union SS2 { floatx16 v; floatx4 q[4]; } w;
            w.v = acc[dt] * aown;
            if (stream == 1) {
                float* sp = &sSx[(((wave & 3) * 64) + lane) * 16];
                *(floatx4*)(sp + 0)  = w.q[0];
                *(floatx4*)(sp + 4)  = w.q[1];
                *(floatx4*)(sp + 8)  = w.q[2];
                *(floatx4*)(sp + 12) = w.q[3];
            }
            __syncthreads();
            if (stream == 0) {
                const float* sp = &sSx[((wave * 64) + lane) * 16];
                #pragma unroll
                for (int g = 0; g < 4; ++g) {
                    floatx4 r = *(const floatx4*)(sp + g * 4);
                    floatx4 o = (w.q[g] + r) * inv;
                    *(floatx4*)(op + dt * 32 + g * 8 + 4 * h) = o;
                }
            }
            __syncthreads();
        }
    }
}

// ==================== legacy fallback (verified, 272 us) ====================
__global__ __launch_bounds__(256, 2)
void attn_fa(const float* __restrict__ Qg, const float* __restrict__ Kg,
             float* __restrict__ Og)
{
    __shared__ __align__(16) _Float16 sKr[KT * 512];
    __shared__ __align__(16) _Float16 sKt[256 * 72];
    __shared__ __align__(16) float    sSx[4 * 2 * 64 * 4];

    const int tid  = threadIdx.x;
    const int lane = tid & 63;
    const int wave = tid >> 6;
    const int quad = lane >> 4;
    const int col  = lane & 15;
    const int wq   = wave & 1;
    const int wg   = wave >> 1;
    const int dbase = wg * 256;

    const int batch = blockIdx.x & 7;
    const int qtile = blockIdx.x >> 3;
    const int qrow  = qtile * 32 + wq * 16 + col;

    const float* qp = Qg + ((size_t)batch * NQ + qrow) * DIM + dbase + quad * 8;
    half8 qf[8];
    #pragma unroll
    for (int dc = 0; dc < 8; ++dc) {
        float4 f0 = *(const float4*)(qp + dc * 32);
        float4 f1 = *(const float4*)(qp + dc * 32 + 4);
        union { unsigned u[4]; half8 hh; } t;
        t.u[0] = PKRT(f0.x, f0.y); t.u[1] = PKRT(f0.z, f0.w);
        t.u[2] = PKRT(f1.x, f1.y); t.u[3] = PKRT(f1.z, f1.w);
        qf[dc] = t.hh;
    }

    floatx4 acc[16];
    #pragma unroll
    for (int i = 0; i < 16; ++i) acc[i] = (floatx4){0.f, 0.f, 0.f, 0.f};

    float m_run = -INFINITY;
    float l_run = 0.f;
    const int keyc = ((col & 3) << 1) | ((col >> 2) & 1);

    for (int kt = 0; kt < NK / KT; ++kt) {
        __syncthreads();
        {
            const float* kp = Kg + ((size_t)batch * NK + kt * KT + wave * 8) * DIM + lane * 8;
            float rv[8][8];
            #pragma unroll
            for (int kk = 0; kk < 8; ++kk) {
                float4 f0 = *(const float4*)(kp + kk * DIM);
                float4 f1 = *(const float4*)(kp + kk * DIM + 4);
                rv[kk][0] = f0.x; rv[kk][1] = f0.y; rv[kk][2] = f0.z; rv[kk][3] = f0.w;
                rv[kk][4] = f1.x; rv[kk][5] = f1.y; rv[kk][6] = f1.z; rv[kk][7] = f1.w;
            }
            #pragma unroll
            for (int kk = 0; kk < 8; ++kk) {
                const int row = wave * 8 + kk;
                const int key = ((row & 3) << 1) | ((row >> 2) & 1);
                uint4 w;
                w.x = PKRT(rv[kk][0], rv[kk][1]); w.y = PKRT(rv[kk][2], rv[kk][3]);
                w.z = PKRT(rv[kk][4], rv[kk][5]); w.w = PKRT(rv[kk][6], rv[kk][7]);
                *(uint4*)&sKr[row * 512 + ((lane ^ key) << 3)] = w;
            }
            #pragma unroll
            for (int dd = 0; dd < 8; ++dd) {
                const int pp = dd >> 1;
                const int b  = dd & 1;
                const int slot = (pp << 6) | lane;
                uint4 w;
                w.x = PKRT(rv[0][dd], rv[1][dd]); w.y = PKRT(rv[2][dd], rv[3][dd]);
                w.z = PKRT(rv[4][dd], rv[5][dd]); w.w = PKRT(rv[6][dd], rv[7][dd]);
                *(uint4*)&sKt[slot * 72 + ((wave ^ pp) << 4) + (b << 3)] = w;
            }
        }
        __syncthreads();

        floatx4 s0 = {0.f, 0.f, 0.f, 0.f}, s1 = {0.f, 0.f, 0.f, 0.f};
        #pragma unroll
        for (int dc = 0; dc < 8; ++dc) {
            const int g = wg * 32 + dc * 4 + quad;
            const int off = ((g ^ keyc) << 3);
            half8 a0 = *(const half8*)&sKr[col * 512 + off];
            half8 a1 = *(const half8*)&sKr[(col + 16) * 512 + off];
            s0 = __builtin_amdgcn_mfma_f32_16x16x32_f16(a0, qf[dc], s0, 0, 0, 0);
            s1 = __builtin_amdgcn_mfma_f32_16x16x32_f16(a1, qf[dc], s1, 0, 0, 0);
        }

        *(floatx4*)&sSx[((wave * 2 + 0) * 64 + lane) * 4] = s0;
        *(floatx4*)&sSx[((wave * 2 + 1) * 64 + lane) * 4] = s1;
        __syncthreads();
        {
            const int pw = wave ^ 2;
            s0 += *(const floatx4*)&sSx[((pw * 2 + 0) * 64 + lane) * 4];
            s1 += *(const floatx4*)&sSx[((pw * 2 + 1) * 64 + lane) * 4];
        }

        float mloc = fmaxf(fmaxf(fmaxf(s0[0], s0[1]), fmaxf(s0[2], s0[3])),
                           fmaxf(fmaxf(s1[0], s1[1]), fmaxf(s1[2], s1[3])));
        mloc = fmaxf(mloc, __shfl_xor(mloc, 16));
        mloc = fmaxf(mloc, __shfl_xor(mloc, 32));
        const float m_new = fmaxf(m_run, mloc);
        const float alpha = exp2f((m_run - m_new) * LOG2E);
        const float p0 = exp2f((s0[0] - m_new) * LOG2E);
        const float p1 = exp2f((s0[1] - m_new) * LOG2E);
        const float p2 = exp2f((s0[2] - m_new) * LOG2E);
        const float p3 = exp2f((s0[3] - m_new) * LOG2E);
        const float p4 = exp2f((s1[0] - m_new) * LOG2E);
        const float p5 = exp2f((s1[1] - m_new) * LOG2E);
        const float p6 = exp2f((s1[2] - m_new) * LOG2E);
        const float p7 = exp2f((s1[3] - m_new) * LOG2E);
        float sloc = ((p0 + p1) + (p2 + p3)) + ((p4 + p5) + (p6 + p7));
        sloc += __shfl_xor(sloc, 16);
        sloc += __shfl_xor(sloc, 32);
        l_run = l_run * alpha + sloc;
        m_run = m_new;

        #pragma unroll
        for (int i = 0; i < 16; ++i) acc[i] *= alpha;

        const unsigned pk00 = PKRT(p0, p1);
        const unsigned pk01 = PKRT(p2, p3);
        const unsigned pk10 = PKRT(p4, p5);
        const unsigned pk11 = PKRT(p6, p7);
        const int srcA = col + ((quad & 1) << 5);
        const int srcB = srcA + 16;
        const unsigned a00 = (unsigned)__shfl((int)pk00, srcA);
        const unsigned a01 = (unsigned)__shfl((int)pk01, srcA);
        const unsigned a10 = (unsigned)__shfl((int)pk10, srcA);
        const unsigned a11 = (unsigned)__shfl((int)pk11, srcA);
        const unsigned b00 = (unsigned)__shfl((int)pk00, srcB);
        const unsigned b01 = (unsigned)__shfl((int)pk01, srcB);
        const unsigned b10 = (unsigned)__shfl((int)pk10, srcB);
        const unsigned b11 = (unsigned)__shfl((int)pk11, srcB);
        const bool hi2 = (quad >= 2);
        union { unsigned u[4]; half8 hh; } pt;
        pt.u[0] = hi2 ? a10 : a00;
        pt.u[1] = hi2 ? a11 : a01;
        pt.u[2] = hi2 ? b10 : b00;
        pt.u[3] = hi2 ? b11 : b01;
        const half8 pf = pt.hh;

        #pragma unroll
        for (int dt = 0; dt < 16; ++dt) {
            const int drow = dbase + dt * 16 + col;
            const int dp = drow >> 1;
            const int off = (((dp & 3) << 6) | (dp >> 2)) * 72
                          + ((quad ^ (dp & 3)) << 4) + ((drow & 1) << 3);
            half8 af = *(const half8*)&sKt[off];
            acc[dt] = __builtin_amdgcn_mfma_f32_16x16x32_f16(af, pf, acc[dt], 0, 0, 0);
        }
    }

    const float inv = 1.f / l_run;
    float* op = Og + ((size_t)batch * NQ + qrow) * DIM + dbase + quad * 4;
    #pragma unroll
    for (int dt = 0; dt < 16; ++dt) {
        floatx4 v = acc[dt] * inv;
        *(floatx4*)(op + dt * 16) = v;
    }
}

extern "C" void kernel_launch(void* const* d_in, const int* in_sizes, int n_in,
                              void* d_out, int out_size, void* d_ws, size_t ws_size,
                              hipStream_t stream) {
    (void)in_sizes; (void)n_in; (void)out_size;
    const float* Q = (const float*)d_in[0];
    const float* K = (const float*)d_in[1];
    float* O = (float*)d_out;
    if (d_ws != nullptr && ws_size >= WS_NEED) {
        char* wsK = (char*)d_ws;
        hipLaunchKernelGGL(prep_k,   dim3(8 * NTILES), dim3(256), 0, stream, K, wsK);
        hipLaunchKernelGGL(attn_fa7, dim3(256),        dim3(512), 0, stream, Q, wsK, O);
    } else {
        hipLaunchKernelGGL(attn_fa,  dim3(512),        dim3(256), 0, stream, Q, K, O);
    }
}